// Round 1
// baseline (10918.395 us; speedup 1.0000x reference)
//
#include <hip/hip_runtime.h>

// DHPM fused forward for MI355X. All math in f32 on the vector ALU.
// Structure: block = 512 threads (8 waves) handles TP=64 points.
//   phase1: z0 = W0*pt+b0; store (sin,cos) packed 2-i-per-float4 in LDS.
//   phase2: per wave a 25-row j-slice; 6-channel accumulation against W1
//           (value, d/dx, d/dy, d/dt, d2/dx2, d2/dy2) with W1 + per-i
//           constants via wave-uniform scalar loads.
//   cross-wave LDS reduction -> 12 outputs + feature vector -> f-net
//   (same pattern, LDS buffer reused).
// d_ws usage: 2*HID*8 floats = 12.8 KB for precomputed per-unit constants
// {ax, ay, at, b0, -ax^2, -ay^2, 0, 0}.

#define HID 200
#define TP 64
#define NWAVE 8
#define NTHREADS (TP * NWAVE)   // 512
#define JPW (HID / NWAVE)       // 25

__global__ void dhpm_prep(const float* __restrict__ Wu0, const float* __restrict__ bu0,
                          const float* __restrict__ Wv0, const float* __restrict__ bv0,
                          float* __restrict__ cst) {
    const int i = blockIdx.x * blockDim.x + threadIdx.x;
    if (i >= 2 * HID) return;
    const float* W0 = (i < HID) ? Wu0 : Wv0;
    const float* b0 = (i < HID) ? bu0 : bv0;
    const int r = (i < HID) ? i : (i - HID);
    const float ax = W0[r * 3 + 0];
    const float ay = W0[r * 3 + 1];
    const float at = W0[r * 3 + 2];
    float* o = cst + i * 8;
    o[0] = ax; o[1] = ay; o[2] = at; o[3] = b0[r];
    o[4] = -ax * ax; o[5] = -ay * ay; o[6] = 0.f; o[7] = 0.f;
}

__device__ __forceinline__ void net_phase(
    const float* __restrict__ cstN,   // [HID][8] per-unit constants
    const float* __restrict__ W1,
    const float* __restrict__ b1,
    const float* __restrict__ W2,
    const float px, const float py, const float ptt,
    const int p, const int wbase,
    float* __restrict__ scf,          // LDS: [HID/2][TP] float4 {s_i,c_i,s_i+1,c_i+1}
    float* __restrict__ accOut)
{
    // ---- phase 1: sin/cos of layer-0 preactivations ----
    for (int ii = 0; ii < JPW; ++ii) {
        const int i = wbase + ii;
        const float* c4 = cstN + i * 8;              // scalar loads (i uniform)
        const float z = fmaf(c4[0], px, fmaf(c4[1], py, fmaf(c4[2], ptt, c4[3])));
        scf[((i >> 1) * TP + p) * 4 + (i & 1) * 2 + 0] = __sinf(z);
        scf[((i >> 1) * TP + p) * 4 + (i & 1) * 2 + 1] = __cosf(z);
    }
    __syncthreads();

    // ---- phase 2: 6-channel layer-1 + epilogue ----
    float av = 0.f, adx = 0.f, ady = 0.f, adt = 0.f, axx = 0.f, ayy = 0.f;
    const float4* __restrict__ scq = (const float4*)scf;
    for (int jj = 0; jj < JPW; ++jj) {
        const int j = wbase + jj;                    // wave-uniform
        const float* __restrict__ row = W1 + j * HID; // scalar loads
        float z1 = 0.f, cx = 0.f, cy = 0.f, ct = 0.f, exx = 0.f, eyy = 0.f;
        #pragma unroll 4
        for (int ip = 0; ip < HID / 2; ++ip) {
            const float4 sc4 = scq[ip * TP + p];     // ds_read_b128: 2 i's
            const float w1a = row[2 * ip + 0];
            const float w1b = row[2 * ip + 1];
            const float* ca = cstN + (2 * ip + 0) * 8;
            const float* cb = cstN + (2 * ip + 1) * 8;
            float m  = w1a * sc4.x;                  // w*sin(z0)
            float tt = w1a * sc4.y;                  // w*cos(z0)
            z1 += m;
            exx = fmaf(m, ca[4], exx);
            eyy = fmaf(m, ca[5], eyy);
            cx  = fmaf(tt, ca[0], cx);
            cy  = fmaf(tt, ca[1], cy);
            ct  = fmaf(tt, ca[2], ct);
            m  = w1b * sc4.z;
            tt = w1b * sc4.w;
            z1 += m;
            exx = fmaf(m, cb[4], exx);
            eyy = fmaf(m, cb[5], eyy);
            cx  = fmaf(tt, cb[0], cx);
            cy  = fmaf(tt, cb[1], cy);
            ct  = fmaf(tt, cb[2], ct);
        }
        z1 += b1[j];
        const float s1 = __sinf(z1);
        const float c1 = __cosf(z1);
        const float w2 = W2[j];
        const float t3 = w2 * c1;
        const float t4 = w2 * s1;
        av  += t4;                                   // value
        adx  = fmaf(t3, cx, adx);                    // d/dx
        ady  = fmaf(t3, cy, ady);                    // d/dy
        adt  = fmaf(t3, ct, adt);                    // d/dt
        axx  = fmaf(t3, exx, axx);                   // d2/dx2 = c1*E - s1*C^2 (x W2)
        axx  = fmaf(-t4 * cx, cx, axx);
        ayy  = fmaf(t3, eyy, ayy);
        ayy  = fmaf(-t4 * cy, cy, ayy);
    }
    accOut[0] = av;  accOut[1] = adx; accOut[2] = ady;
    accOut[3] = adt; accOut[4] = axx; accOut[5] = ayy;
}

__global__ __launch_bounds__(NTHREADS, 1) void dhpm_main(
    const float* __restrict__ inp, const float* __restrict__ cst,
    const float* __restrict__ Wu1, const float* __restrict__ bu1,
    const float* __restrict__ Wu2, const float* __restrict__ bu2,
    const float* __restrict__ Wv1, const float* __restrict__ bv1,
    const float* __restrict__ Wv2, const float* __restrict__ bv2,
    const float* __restrict__ Wf0, const float* __restrict__ bf0,
    const float* __restrict__ Wf1, const float* __restrict__ bf1,
    const float* __restrict__ Wf2, const float* __restrict__ bf2,
    float* __restrict__ out, const int Np)
{
    __shared__ float scf[(HID / 2) * TP * 4];   // 102400 B (reused by f-net)
    __shared__ float red[NWAVE * TP * 6];       // 12288 B
    __shared__ float featL[TP * 13];            // 3328 B (pad 13 vs bank conflicts)

    const int t = threadIdx.x;
    const int p = t & 63;
    const int w = __builtin_amdgcn_readfirstlane(t >> 6);
    const int wbase = w * JPW;
    const int bb = blockIdx.x * TP;
    const int gp = bb + p;
    const float px  = inp[gp * 3 + 0];
    const float py  = inp[gp * 3 + 1];
    const float ptt = inp[gp * 3 + 2];

    float acc[6];

    // ================= u-net =================
    net_phase(cst, Wu1, bu1, Wu2, px, py, ptt, p, wbase, scf, acc);
    #pragma unroll
    for (int k = 0; k < 6; ++k) red[(w * TP + p) * 6 + k] = acc[k];
    __syncthreads();
    if (t < 6 * TP) {
        const int pp = t & 63;
        const int k  = t >> 6;          // 0..5 : val,dx,dy,dt,dxx,dyy
        float s = 0.f;
        #pragma unroll
        for (int ww = 0; ww < NWAVE; ++ww) s += red[(ww * TP + pp) * 6 + k];
        if (k == 0) s += bu2[0];
        const int col = (k == 0) ? 0 : (k == 1) ? 4 : (k == 2) ? 6
                      : (k == 3) ? 2 : (k == 4) ? 5 : 7;
        out[col * Np + bb + pp] = s;
        featL[pp * 13 + col] = s;
    }

    // ================= v-net =================
    // (scf dead: all phase-2(u) reads completed before the sync above)
    net_phase(cst + HID * 8, Wv1, bv1, Wv2, px, py, ptt, p, wbase, scf, acc);
    #pragma unroll
    for (int k = 0; k < 6; ++k) red[(w * TP + p) * 6 + k] = acc[k];
    __syncthreads();
    if (t < 6 * TP) {
        const int pp = t & 63;
        const int k  = t >> 6;
        float s = 0.f;
        #pragma unroll
        for (int ww = 0; ww < NWAVE; ++ww) s += red[(ww * TP + pp) * 6 + k];
        if (k == 0) s += bv2[0];
        const int col = (k == 0) ? 1 : (k == 1) ? 8 : (k == 2) ? 10
                      : (k == 3) ? 3 : (k == 4) ? 9 : 11;
        out[col * Np + bb + pp] = s;
        featL[pp * 13 + col] = s;
    }
    __syncthreads();   // featL complete before f-net reads it

    // ================= f-net layer 0 =================
    for (int ii = 0; ii < JPW; ++ii) {
        const int i = wbase + ii;
        float z = bf0[i];
        #pragma unroll
        for (int k = 0; k < 12; ++k)
            z = fmaf(Wf0[i * 12 + k], featL[p * 13 + k], z);
        scf[((i >> 1) * TP + p) * 2 + (i & 1)] = __sinf(z);  // float2-packed
    }
    __syncthreads();

    // ================= f-net layer 1 + 2 =================
    float fa = 0.f, fb = 0.f;
    const float2* __restrict__ hf2 = (const float2*)scf;
    for (int jj = 0; jj < JPW; ++jj) {
        const int j = wbase + jj;
        const float* __restrict__ row = Wf1 + j * HID;   // scalar loads
        float z = 0.f;
        #pragma unroll 4
        for (int ip = 0; ip < HID / 2; ++ip) {
            const float2 h2 = hf2[ip * TP + p];
            z = fmaf(row[2 * ip + 0], h2.x, z);
            z = fmaf(row[2 * ip + 1], h2.y, z);
        }
        z += bf1[j];
        const float h = __sinf(z);
        fa = fmaf(Wf2[j], h, fa);
        fb = fmaf(Wf2[HID + j], h, fb);
    }
    red[(w * TP + p) * 6 + 0] = fa;
    red[(w * TP + p) * 6 + 1] = fb;
    __syncthreads();
    if (t < 2 * TP) {
        const int pp = t & 63;
        const int k  = t >> 6;
        float s = 0.f;
        #pragma unroll
        for (int ww = 0; ww < NWAVE; ++ww) s += red[(ww * TP + pp) * 6 + k];
        s += bf2[k];
        out[(12 + k) * Np + bb + pp] = s;
    }
}

extern "C" void kernel_launch(void* const* d_in, const int* in_sizes, int n_in,
                              void* d_out, int out_size, void* d_ws, size_t ws_size,
                              hipStream_t stream) {
    const float* inp = (const float*)d_in[0];
    const float* Wu0 = (const float*)d_in[1];  const float* bu0 = (const float*)d_in[2];
    const float* Wu1 = (const float*)d_in[3];  const float* bu1 = (const float*)d_in[4];
    const float* Wu2 = (const float*)d_in[5];  const float* bu2 = (const float*)d_in[6];
    const float* Wv0 = (const float*)d_in[7];  const float* bv0 = (const float*)d_in[8];
    const float* Wv1 = (const float*)d_in[9];  const float* bv1 = (const float*)d_in[10];
    const float* Wv2 = (const float*)d_in[11]; const float* bv2 = (const float*)d_in[12];
    const float* Wf0 = (const float*)d_in[13]; const float* bf0 = (const float*)d_in[14];
    const float* Wf1 = (const float*)d_in[15]; const float* bf1 = (const float*)d_in[16];
    const float* Wf2 = (const float*)d_in[17]; const float* bf2 = (const float*)d_in[18];
    float* out = (float*)d_out;
    float* cst = (float*)d_ws;      // needs 12.8 KB scratch

    const int Np = in_sizes[0] / 3;  // 262144
    dhpm_prep<<<1, NTHREADS, 0, stream>>>(Wu0, bu0, Wv0, bv0, cst);
    dhpm_main<<<Np / TP, NTHREADS, 0, stream>>>(
        inp, cst, Wu1, bu1, Wu2, bu2, Wv1, bv1, Wv2, bv2,
        Wf0, bf0, Wf1, bf1, Wf2, bf2, out, Np);
}

// Round 2
// 1882.029 us; speedup vs baseline: 5.8014x; 5.8014x over previous
//
#include <hip/hip_runtime.h>

// DHPM fused forward, MFMA formulation (MI355X / gfx950).
//
// Math: u(x,y,t) = W2 sin(W1 sin(W0 p + b0) + b1) + b2. All derivatives are
// analytic. Per point, layer-1 needs 6 simultaneous matvecs against W1 with
// per-i diagonal scalings g_c(i) in {1, -ax^2, -ay^2, ax, ay, at}:
//   Y_c[j] = sum_i W1[j,i] * A_{grp(c)}[i] * g_c[i],  A_sin = sin(z0), A_cos = cos(z0)
// => GEMM with A = [sin;cos] (per 128-point block, f16, LDS, XOR-swizzled)
//    and B'_c = W1 row-scaled by g_c (built on the fly into LDS, f16).
// Epilogue per (point j): z1 = Y0+b1; s1,c1; accumulate
//   val += w2 s1; d* += w2 c1 Y_{3,4,5}; dxx += w2(c1 Y1 - s1 Y3^2); dyy += w2(c1 Y2 - s1 Y4^2).
// f-net: same structure, 1 channel.
//
// Block: 512 thr (8 waves), 128 points. Waves: q=w&3 pt-quarter (2 mtiles),
// g=w>>2 channel-triple (g0: sin channels {val,xx,yy}; g1: cos {x,y,t}).
// A-frags register-cached across all 13 n-tiles (56 VGPR).

#define HID 200
#define NPTS 128
#define NTHREADS 512
#define NT_TILES 13       // 208 >= 200 cols of W1 (j)
#define KT_TILES 7        // 224 >= 200 contraction (i)
#define A_LDK 256         // f16 row stride of A (swizzled, 512B)
#define B_LDK 232         // f16 row stride of B' (464B = 116w == 20 mod 32)
#define Y_LDP 132         // f32 row stride of Y

typedef _Float16 f16;
typedef _Float16 f16x2 __attribute__((ext_vector_type(2)));
typedef _Float16 f16x8 __attribute__((ext_vector_type(8)));
typedef float f32x4 __attribute__((ext_vector_type(4)));

// LDS region0 byte offsets (A region [2][128][256]f16 = 131072 is reused)
#define OFF_BST 0                     // [6][16][232] f16 = 44544
#define OFF_Y   45056                 // [6][16][132] f32 = 50688 (end 95744)
#define OFF_BF  69632                 // f-net B [16][232] f16 = 7424 (Af ends 65536)
#define OFF_YF  77824                 // f-net Y [16][132] f32 = 8448 (end 86272)
#define REGION0 131072

__device__ __forceinline__ void run_net(
    const float* __restrict__ W0, const float* __restrict__ b0,
    const float* __restrict__ W1, const float* __restrict__ b1,
    const float* __restrict__ W2, const float* __restrict__ b2,
    const float x, const float y, const float tt,
    const int cVal, const int cDx, const int cDxx,
    const int cDy, const int cDyy, const int cDt,
    char* __restrict__ LDSR, float* __restrict__ featL,
    float* __restrict__ out, const int Np, const int gp0)
{
    const int t = threadIdx.x;
    const int lane = t & 63;
    const int w = __builtin_amdgcn_readfirstlane(t >> 6);
    const int q = w & 3;      // pt-quarter: points [32q, 32q+32)
    const int g = w >> 2;     // 0: sin-group channels, 1: cos-group

    // ---------------- A fill: sin/cos(z0) f16, swizzled ----------------
    __syncthreads();
    {
        f16* Ah = (f16*)LDSR;
        const int p = t & 127;
        const int quarter = t >> 7;
        const int i0 = quarter * 50;
        for (int ii = 0; ii < 50; ii += 2) {
            const int i = i0 + ii;
            const float axa = W0[i*3+0], aya = W0[i*3+1], ata = W0[i*3+2];
            const float axb = W0[i*3+3], ayb = W0[i*3+4], atb = W0[i*3+5];
            const float za = fmaf(axa, x, fmaf(aya, y, fmaf(ata, tt, b0[i])));
            const float zb = fmaf(axb, x, fmaf(ayb, y, fmaf(atb, tt, b0[i+1])));
            float sa, ca, sb, cb;
            __sincosf(za, &sa, &ca);
            __sincosf(zb, &sb, &cb);
            const int isw = i ^ ((p & 7) << 3);
            f16x2 vs; vs[0] = (f16)sa; vs[1] = (f16)sb;
            f16x2 vc; vc[0] = (f16)ca; vc[1] = (f16)cb;
            *(f16x2*)&Ah[p*A_LDK + isw]         = vs;
            *(f16x2*)&Ah[(128 + p)*A_LDK + isw] = vc;
        }
        if (quarter == 3) {
            #pragma unroll
            for (int i = 200; i < 224; i += 2) {
                const int isw = i ^ ((p & 7) << 3);
                f16x2 z2; z2[0] = (f16)0.f; z2[1] = (f16)0.f;
                *(f16x2*)&Ah[p*A_LDK + isw]         = z2;
                *(f16x2*)&Ah[(128 + p)*A_LDK + isw] = z2;
            }
        }
    }
    __syncthreads();

    // ---------------- A-frag register cache (per wave) ----------------
    f16x8 afrag[2][KT_TILES];
    {
        const f16* Ah = (const f16*)LDSR;
        #pragma unroll
        for (int mt = 0; mt < 2; ++mt) {
            const int row = g*128 + q*32 + mt*16 + (lane & 15);
            #pragma unroll
            for (int kt = 0; kt < KT_TILES; ++kt) {
                const int kidx = (kt*32 + (lane >> 4)*8) ^ ((row & 7) << 3);
                afrag[mt][kt] = *(const f16x8*)&Ah[row*A_LDK + kidx];
            }
        }
    }
    __syncthreads();   // A region now reusable for Bst/Y

    float pv = 0.f, pxx = 0.f, pyy = 0.f, pdx = 0.f, pdy = 0.f, pdt = 0.f;

    f16* Bst = (f16*)(LDSR + OFF_BST);
    float* Yb = (float*)(LDSR + OFF_Y);

    for (int nt = 0; nt < NT_TILES; ++nt) {
        // ---- stage B' slice: rows = c*16+nl, B'[row][k] = W1[n][k]*g_c[k] ----
        for (int e = t; e < 96*116; e += NTHREADS) {
            const int row = e / 116;
            const int kp  = (e - row*116) * 2;
            const int c   = row >> 4;
            const int n   = nt*16 + (row & 15);
            f16x2 v2; v2[0] = (f16)0.f; v2[1] = (f16)0.f;
            if (n < HID && kp < HID) {
                const float w1a = W1[n*HID + kp];
                const float w1b = W1[n*HID + kp + 1];
                const float ax0 = W0[kp*3+0], ay0 = W0[kp*3+1], at0 = W0[kp*3+2];
                const float ax1 = W0[kp*3+3], ay1 = W0[kp*3+4], at1 = W0[kp*3+5];
                float g0, g1;
                if      (c == 0) { g0 = 1.f;      g1 = 1.f;      }
                else if (c == 1) { g0 = -ax0*ax0; g1 = -ax1*ax1; }
                else if (c == 2) { g0 = -ay0*ay0; g1 = -ay1*ay1; }
                else if (c == 3) { g0 = ax0;      g1 = ax1;      }
                else if (c == 4) { g0 = ay0;      g1 = ay1;      }
                else             { g0 = at0;      g1 = at1;      }
                v2[0] = (f16)(w1a * g0);
                v2[1] = (f16)(w1b * g1);
            }
            *(f16x2*)(Bst + row*B_LDK + kp) = v2;
        }
        __syncthreads();

        // ---- GEMM: 3 channels x 2 mtiles, K = 7x32 ----
        f32x4 acc[3][2];
        #pragma unroll
        for (int cc = 0; cc < 3; ++cc)
            #pragma unroll
            for (int mt = 0; mt < 2; ++mt) {
                f32x4 z; z[0]=0.f; z[1]=0.f; z[2]=0.f; z[3]=0.f;
                acc[cc][mt] = z;
            }
        #pragma unroll
        for (int kt = 0; kt < KT_TILES; ++kt) {
            f16x8 bfr[3];
            #pragma unroll
            for (int cc = 0; cc < 3; ++cc)
                bfr[cc] = *(const f16x8*)&Bst[((g*3 + cc)*16 + (lane & 15))*B_LDK
                                              + kt*32 + (lane >> 4)*8];
            #pragma unroll
            for (int cc = 0; cc < 3; ++cc)
                #pragma unroll
                for (int mt = 0; mt < 2; ++mt)
                    acc[cc][mt] = __builtin_amdgcn_mfma_f32_16x16x32_f16(
                        afrag[mt][kt], bfr[cc], acc[cc][mt], 0, 0, 0);
        }
        // C layout: col j = lane&15, row pt = (lane>>4)*4 + r  [m89-verified]
        #pragma unroll
        for (int cc = 0; cc < 3; ++cc)
            #pragma unroll
            for (int mt = 0; mt < 2; ++mt)
                *(f32x4*)&Yb[((g*3 + cc)*16 + (lane & 15))*Y_LDP
                             + q*32 + mt*16 + (lane >> 4)*4] = acc[cc][mt];
        __syncthreads();

        // ---- epilogue: per (point, j) combine; per-thread partials ----
        {
            const int p = t & 127, js = t >> 7;
            #pragma unroll
            for (int jj4 = 0; jj4 < 4; ++jj4) {
                const int jj = js*4 + jj4;
                const int j = nt*16 + jj;
                if (j < HID) {
                    const float Y0 = Yb[(0*16 + jj)*Y_LDP + p];
                    const float Y1 = Yb[(1*16 + jj)*Y_LDP + p];
                    const float Y2 = Yb[(2*16 + jj)*Y_LDP + p];
                    const float Y3 = Yb[(3*16 + jj)*Y_LDP + p];
                    const float Y4 = Yb[(4*16 + jj)*Y_LDP + p];
                    const float Y5 = Yb[(5*16 + jj)*Y_LDP + p];
                    float s1, c1;
                    __sincosf(Y0 + b1[j], &s1, &c1);
                    const float w2 = W2[j];
                    const float wc = w2*c1, ws = w2*s1;
                    pv  += ws;
                    pxx = fmaf(wc, Y1, fmaf(-ws*Y3, Y3, pxx));
                    pyy = fmaf(wc, Y2, fmaf(-ws*Y4, Y4, pyy));
                    pdx = fmaf(wc, Y3, pdx);
                    pdy = fmaf(wc, Y4, pdy);
                    pdt = fmaf(wc, Y5, pdt);
                }
            }
        }
        // next staging (Bst) is safe: its readers finished before the Y barrier;
        // next Y write happens after next stage barrier (all epilogues done).
    }

    // ---------------- combine the 4 j-slot partials per point ----------------
    {
        float* red = (float*)LDSR;   // [128][4][6], Bst region (dead)
        const int p = t & 127, js = t >> 7;
        red[(p*4 + js)*6 + 0] = pv;
        red[(p*4 + js)*6 + 1] = pxx;
        red[(p*4 + js)*6 + 2] = pyy;
        red[(p*4 + js)*6 + 3] = pdx;
        red[(p*4 + js)*6 + 4] = pdy;
        red[(p*4 + js)*6 + 5] = pdt;
    }
    __syncthreads();
    if (t < NPTS) {
        const float* red = (const float*)LDSR;
        float s[6] = {0.f, 0.f, 0.f, 0.f, 0.f, 0.f};
        #pragma unroll
        for (int sl = 0; sl < 4; ++sl)
            #pragma unroll
            for (int c = 0; c < 6; ++c) s[c] += red[(t*4 + sl)*6 + c];
        const int gp = gp0 + t;
        const float val = s[0] + b2[0];
        out[cVal*Np + gp] = val;  featL[t*13 + cVal] = val;
        out[cDxx*Np + gp] = s[1]; featL[t*13 + cDxx] = s[1];
        out[cDyy*Np + gp] = s[2]; featL[t*13 + cDyy] = s[2];
        out[cDx*Np  + gp] = s[3]; featL[t*13 + cDx]  = s[3];
        out[cDy*Np  + gp] = s[4]; featL[t*13 + cDy]  = s[4];
        out[cDt*Np  + gp] = s[5]; featL[t*13 + cDt]  = s[5];
    }
}

__global__ __launch_bounds__(NTHREADS) void dhpm_mfma(
    const float* __restrict__ inp,
    const float* __restrict__ Wu0, const float* __restrict__ bu0,
    const float* __restrict__ Wu1, const float* __restrict__ bu1,
    const float* __restrict__ Wu2, const float* __restrict__ bu2,
    const float* __restrict__ Wv0, const float* __restrict__ bv0,
    const float* __restrict__ Wv1, const float* __restrict__ bv1,
    const float* __restrict__ Wv2, const float* __restrict__ bv2,
    const float* __restrict__ Wf0, const float* __restrict__ bf0,
    const float* __restrict__ Wf1, const float* __restrict__ bf1,
    const float* __restrict__ Wf2, const float* __restrict__ bf2,
    float* __restrict__ out, const int Np)
{
    __shared__ __align__(16) char LDSR[REGION0];
    __shared__ float featL[NPTS * 13];

    const int t = threadIdx.x;
    const int lane = t & 63;
    const int w = __builtin_amdgcn_readfirstlane(t >> 6);
    const int gp0 = blockIdx.x * NPTS;
    const int pme = t & 127;
    const float x  = inp[(gp0 + pme)*3 + 0];
    const float y  = inp[(gp0 + pme)*3 + 1];
    const float tt = inp[(gp0 + pme)*3 + 2];

    run_net(Wu0, bu0, Wu1, bu1, Wu2, bu2, x, y, tt,
            0, 4, 5, 6, 7, 2, LDSR, featL, out, Np, gp0);
    run_net(Wv0, bv0, Wv1, bv1, Wv2, bv2, x, y, tt,
            1, 8, 9, 10, 11, 3, LDSR, featL, out, Np, gp0);

    // ======================= f-net =======================
    __syncthreads();   // featL complete; LDSR reusable
    {
        f16* Af = (f16*)LDSR;   // [128][256] f16, swizzled (sin rows only)
        const int p = t & 127;
        const int quarter = t >> 7;
        float fv[12];
        #pragma unroll
        for (int k = 0; k < 12; ++k) fv[k] = featL[p*13 + k];
        const int i0 = quarter * 50;
        for (int ii = 0; ii < 50; ii += 2) {
            const int i = i0 + ii;
            float za = bf0[i], zb = bf0[i+1];
            #pragma unroll
            for (int k = 0; k < 12; ++k) {
                za = fmaf(Wf0[i*12 + k],      fv[k], za);
                zb = fmaf(Wf0[(i+1)*12 + k],  fv[k], zb);
            }
            const int isw = i ^ ((p & 7) << 3);
            f16x2 v2; v2[0] = (f16)__sinf(za); v2[1] = (f16)__sinf(zb);
            *(f16x2*)&Af[p*A_LDK + isw] = v2;
        }
        if (quarter == 3) {
            #pragma unroll
            for (int i = 200; i < 224; i += 2) {
                const int isw = i ^ ((p & 7) << 3);
                f16x2 z2; z2[0] = (f16)0.f; z2[1] = (f16)0.f;
                *(f16x2*)&Af[p*A_LDK + isw] = z2;
            }
        }
    }
    __syncthreads();

    f16x8 affrag[KT_TILES];
    {
        const f16* Af = (const f16*)LDSR;
        const int row = w*16 + (lane & 15);
        #pragma unroll
        for (int kt = 0; kt < KT_TILES; ++kt) {
            const int kidx = (kt*32 + (lane >> 4)*8) ^ ((row & 7) << 3);
            affrag[kt] = *(const f16x8*)&Af[row*A_LDK + kidx];
        }
    }
    __syncthreads();

    float pf0 = 0.f, pf1 = 0.f;
    f16* Bf = (f16*)(LDSR + OFF_BF);
    float* Yf = (float*)(LDSR + OFF_YF);

    for (int nt = 0; nt < NT_TILES; ++nt) {
        for (int e = t; e < 16*116; e += NTHREADS) {
            const int row = e / 116;
            const int kp = (e - row*116) * 2;
            const int n = nt*16 + row;
            f16x2 v2; v2[0] = (f16)0.f; v2[1] = (f16)0.f;
            if (n < HID && kp < HID) {
                v2[0] = (f16)Wf1[n*HID + kp];
                v2[1] = (f16)Wf1[n*HID + kp + 1];
            }
            *(f16x2*)(Bf + row*B_LDK + kp) = v2;
        }
        __syncthreads();

        f32x4 facc; facc[0]=0.f; facc[1]=0.f; facc[2]=0.f; facc[3]=0.f;
        #pragma unroll
        for (int kt = 0; kt < KT_TILES; ++kt) {
            const f16x8 bfr = *(const f16x8*)&Bf[(lane & 15)*B_LDK
                                                 + kt*32 + (lane >> 4)*8];
            facc = __builtin_amdgcn_mfma_f32_16x16x32_f16(affrag[kt], bfr, facc, 0, 0, 0);
        }
        *(f32x4*)&Yf[(lane & 15)*Y_LDP + w*16 + (lane >> 4)*4] = facc;
        __syncthreads();

        {
            const int p = t & 127, js = t >> 7;
            #pragma unroll
            for (int jj4 = 0; jj4 < 4; ++jj4) {
                const int jj = js*4 + jj4;
                const int j = nt*16 + jj;
                if (j < HID) {
                    const float h = __sinf(Yf[jj*Y_LDP + p] + bf1[j]);
                    pf0 = fmaf(Wf2[j],       h, pf0);
                    pf1 = fmaf(Wf2[HID + j], h, pf1);
                }
            }
        }
    }

    {
        float* red = (float*)LDSR;   // [128][4][2]
        const int p = t & 127, js = t >> 7;
        red[(p*4 + js)*2 + 0] = pf0;
        red[(p*4 + js)*2 + 1] = pf1;
    }
    __syncthreads();
    if (t < NPTS) {
        const float* red = (const float*)LDSR;
        float s0 = bf2[0], s1 = bf2[1];
        #pragma unroll
        for (int sl = 0; sl < 4; ++sl) {
            s0 += red[(t*4 + sl)*2 + 0];
            s1 += red[(t*4 + sl)*2 + 1];
        }
        out[12*Np + gp0 + t] = s0;
        out[13*Np + gp0 + t] = s1;
    }
}

extern "C" void kernel_launch(void* const* d_in, const int* in_sizes, int n_in,
                              void* d_out, int out_size, void* d_ws, size_t ws_size,
                              hipStream_t stream) {
    const float* inp = (const float*)d_in[0];
    const float* Wu0 = (const float*)d_in[1];  const float* bu0 = (const float*)d_in[2];
    const float* Wu1 = (const float*)d_in[3];  const float* bu1 = (const float*)d_in[4];
    const float* Wu2 = (const float*)d_in[5];  const float* bu2 = (const float*)d_in[6];
    const float* Wv0 = (const float*)d_in[7];  const float* bv0 = (const float*)d_in[8];
    const float* Wv1 = (const float*)d_in[9];  const float* bv1 = (const float*)d_in[10];
    const float* Wv2 = (const float*)d_in[11]; const float* bv2 = (const float*)d_in[12];
    const float* Wf0 = (const float*)d_in[13]; const float* bf0 = (const float*)d_in[14];
    const float* Wf1 = (const float*)d_in[15]; const float* bf1 = (const float*)d_in[16];
    const float* Wf2 = (const float*)d_in[17]; const float* bf2 = (const float*)d_in[18];
    float* out = (float*)d_out;

    const int Np = in_sizes[0] / 3;  // 262144
    dhpm_mfma<<<Np / NPTS, NTHREADS, 0, stream>>>(
        inp, Wu0, bu0, Wu1, bu1, Wu2, bu2, Wv0, bv0, Wv1, bv1, Wv2, bv2,
        Wf0, bf0, Wf1, bf1, Wf2, bf2, out, Np);
}

// Round 3
// 648.253 us; speedup vs baseline: 16.8428x; 2.9032x over previous
//
#include <hip/hip_runtime.h>

// DHPM fused forward v3 (MI355X / gfx950).
// - prep kernel precomputes, into d_ws (f16, padded):
//     B'u/B'v: [13 nt][6ch][16 j][232 k]  (W1 row-scaled by {1,-ax^2,-ay^2,ax,ay,at})
//     B'f:     [13 nt][16 j][232 k]       (Wf1)
//     cst u/v: [200][4] f32 {ax,ay,at,b0};  cf0: [200][16] f32 {Wf0 row, bf0}
// - main kernel: 512 thr / 128 pts / block. Waves: q=w&3 point-quarter,
//   g=w>>2 channel-triple (g0: sin-side {val,xx,yy}, g1: cos-side {x,y,t}).
//   A-frags (sin/cos of z0) computed straight into registers.
//   B' staged per nt via global_load_lds(16B). Per-point partials live in
//   registers; only Y0/Yx/Yy cross the g-boundary through a small LDS
//   exchange buffer. Final j-reduction = shfl_xor butterfly over 16 lanes.

#define HID 200
#define NPTS 128
#define NTHREADS 512
#define NT 13
#define KT 7
#define BLDK 232          // f16 row stride (464 B; 116w % 32 banks -> 2-way, free)
#define BCHUNK 45056      // 6*16*232*2 = 44544 -> padded to 44*1024
#define FCHUNK 8192       // 16*232*2 = 7424 -> padded to 8*1024
#define XLDP 132          // exchange row stride (f32)

#define OFF_U  0
#define OFF_V  585728     // 13*45056
#define OFF_F  1171456    // 2*13*45056
#define OFF_CU 1277952    // OFF_F + 13*8192
#define OFF_CV 1281152
#define OFF_CF 1284352    // 200*64B -> end 1297152

typedef _Float16 f16;
typedef _Float16 f16x2 __attribute__((ext_vector_type(2)));
typedef _Float16 f16x8 __attribute__((ext_vector_type(8)));
typedef float f32x4 __attribute__((ext_vector_type(4)));

#define GLDS16(gp, lp) __builtin_amdgcn_global_load_lds( \
    (const __attribute__((address_space(1))) void*)(gp), \
    (__attribute__((address_space(3))) void*)(lp), 16, 0, 0)

__global__ __launch_bounds__(256) void dhpm_prep(
    const float* __restrict__ Wu0, const float* __restrict__ bu0, const float* __restrict__ Wu1,
    const float* __restrict__ Wv0, const float* __restrict__ bv0, const float* __restrict__ Wv1,
    const float* __restrict__ Wf0, const float* __restrict__ bf0, const float* __restrict__ Wf1,
    char* __restrict__ ws)
{
    const int id = blockIdx.x * blockDim.x + threadIdx.x;
    const int nB = 2 * NT * 96 * 116;   // 289536
    const int nF = NT * 16 * 116;       // 24128
    if (id < nB) {
        int e = id;
        const int net = e / (NT*96*116); e -= net * (NT*96*116);
        const int nt  = e / (96*116);    e -= nt * (96*116);
        const int row = e / 116;
        const int k2  = e - row*116;
        const int ch  = row >> 4;
        const int j   = nt*16 + (row & 15);
        const int k   = k2*2;
        const float* W0 = net ? Wv0 : Wu0;
        const float* W1 = net ? Wv1 : Wu1;
        f16x2 v; v[0] = (f16)0.f; v[1] = (f16)0.f;
        if (j < HID) {
            #pragma unroll
            for (int s = 0; s < 2; ++s) {
                const int ks = k + s;
                if (ks < HID) {
                    const float w1 = W1[j*HID + ks];
                    const float ax = W0[ks*3+0], ay = W0[ks*3+1], at = W0[ks*3+2];
                    float gg;
                    if      (ch == 0) gg = 1.f;
                    else if (ch == 1) gg = -ax*ax;
                    else if (ch == 2) gg = -ay*ay;
                    else if (ch == 3) gg = ax;
                    else if (ch == 4) gg = ay;
                    else              gg = at;
                    v[s] = (f16)(w1 * gg);
                }
            }
        }
        *(f16x2*)(ws + (net ? OFF_V : OFF_U) + nt*BCHUNK + row*464 + k2*4) = v;
        return;
    }
    if (id < nB + nF) {
        int e = id - nB;
        const int nt  = e / (16*116);  e -= nt * (16*116);
        const int row = e / 116;
        const int k2  = e - row*116;
        const int j   = nt*16 + row;
        const int k   = k2*2;
        f16x2 v; v[0] = (f16)0.f; v[1] = (f16)0.f;
        if (j < HID) {
            if (k     < HID) v[0] = (f16)Wf1[j*HID + k];
            if (k + 1 < HID) v[1] = (f16)Wf1[j*HID + k + 1];
        }
        *(f16x2*)(ws + OFF_F + nt*FCHUNK + row*464 + k2*4) = v;
        return;
    }
    if (id < nB + nF + 400) {
        const int e = id - nB - nF;
        const int net = e / HID;
        const int r   = e - net*HID;
        const float* W0 = net ? Wv0 : Wu0;
        const float* b0 = net ? bv0 : bu0;
        float4 c;
        c.x = W0[r*3+0]; c.y = W0[r*3+1]; c.z = W0[r*3+2]; c.w = b0[r];
        *(float4*)(ws + (net ? OFF_CV : OFF_CU) + r*16) = c;
        return;
    }
    if (id < nB + nF + 400 + HID) {
        const int i = id - nB - nF - 400;
        float4 c0, c1, c2, c3;
        c0.x = Wf0[i*12+0];  c0.y = Wf0[i*12+1];  c0.z = Wf0[i*12+2];  c0.w = Wf0[i*12+3];
        c1.x = Wf0[i*12+4];  c1.y = Wf0[i*12+5];  c1.z = Wf0[i*12+6];  c1.w = Wf0[i*12+7];
        c2.x = Wf0[i*12+8];  c2.y = Wf0[i*12+9];  c2.z = Wf0[i*12+10]; c2.w = Wf0[i*12+11];
        c3.x = bf0[i]; c3.y = 0.f; c3.z = 0.f; c3.w = 0.f;
        char* p = ws + OFF_CF + i*64;
        *(float4*)(p)      = c0;
        *(float4*)(p + 16) = c1;
        *(float4*)(p + 32) = c2;
        *(float4*)(p + 48) = c3;
    }
}

__device__ __forceinline__ void run_net(
    const float* __restrict__ inp, const char* __restrict__ ws,
    const int cstOff, const int bOff,
    const float* __restrict__ b1, const float* __restrict__ W2, const float b2s,
    const int colV, const int colX, const int colXX,
    const int colY, const int colYY, const int colT,
    char* __restrict__ Bst, float* __restrict__ exch, float* __restrict__ featL,
    float* __restrict__ out, const int Np, const int gp0)
{
    const int t = threadIdx.x;
    const int lane = t & 63;
    const int w = __builtin_amdgcn_readfirstlane(t >> 6);
    const int q = w & 3, g = w >> 2;
    const int jl = lane & 15, klo = lane >> 4;

    const char* bsrc = ws + bOff;

    // issue stage of nt=0 (overlaps A-build)
    for (int c = w; c < 44; c += 8)
        GLDS16(bsrc + c*1024 + lane*16, Bst + c*1024);

    // ---- A fragments straight into registers ----
    f16x8 afrag[2][KT];
    {
        const float4* cst = (const float4*)(ws + cstOff);
        #pragma unroll
        for (int mt = 0; mt < 2; ++mt) {
            const int prow = q*32 + mt*16 + jl;
            const float px = inp[(gp0+prow)*3+0];
            const float py = inp[(gp0+prow)*3+1];
            const float pz = inp[(gp0+prow)*3+2];
            #pragma unroll
            for (int kt = 0; kt < KT; ++kt) {
                f16x8 f;
                #pragma unroll
                for (int e = 0; e < 8; ++e) {
                    const int i = kt*32 + klo*8 + e;
                    const float4 c = cst[(i < HID) ? i : 0];   // pad cols hit zeroed B'
                    const float z = fmaf(c.x, px, fmaf(c.y, py, fmaf(c.z, pz, c.w)));
                    float sv;
                    if (g == 0) sv = __sinf(z); else sv = __cosf(z);
                    f[e] = (f16)sv;
                }
                afrag[mt][kt] = f;
            }
        }
    }

    float pA[2][4] = {{0,0,0,0},{0,0,0,0}};
    float pB[2][4] = {{0,0,0,0},{0,0,0,0}};
    float pC[2][4] = {{0,0,0,0},{0,0,0,0}};

    __syncthreads();   // Bst(0) ready (vmcnt drained); prev-net exch reads done

    for (int nt = 0; nt < NT; ++nt) {
        // ---- MFMA: 3 channels x 2 mtiles, K = 7x32 ----
        f32x4 acc[3][2];
        #pragma unroll
        for (int cc = 0; cc < 3; ++cc)
            #pragma unroll
            for (int mt = 0; mt < 2; ++mt) {
                f32x4 z = {0.f, 0.f, 0.f, 0.f};
                acc[cc][mt] = z;
            }
        const f16* BH = (const f16*)Bst;
        #pragma unroll
        for (int kt = 0; kt < KT; ++kt) {
            #pragma unroll
            for (int cc = 0; cc < 3; ++cc) {
                const f16x8 bfr = *(const f16x8*)&BH[((g*3+cc)*16 + jl)*BLDK + kt*32 + klo*8];
                acc[cc][0] = __builtin_amdgcn_mfma_f32_16x16x32_f16(afrag[0][kt], bfr, acc[cc][0], 0,0,0);
                acc[cc][1] = __builtin_amdgcn_mfma_f32_16x16x32_f16(afrag[1][kt], bfr, acc[cc][1], 0,0,0);
            }
        }

        // ---- cross-group exchange: Y0 (g0->g1), Yx,Yy (g1->g0) ----
        #pragma unroll
        for (int mt = 0; mt < 2; ++mt) {
            const int pt0 = q*32 + mt*16 + klo*4;
            if (g == 0) {
                *(f32x4*)&exch[(0*16 + jl)*XLDP + pt0] = acc[0][mt];
            } else {
                *(f32x4*)&exch[(1*16 + jl)*XLDP + pt0] = acc[0][mt];
                *(f32x4*)&exch[(2*16 + jl)*XLDP + pt0] = acc[1][mt];
            }
        }
        __syncthreads();   // exch ready; Bst fully consumed

        if (nt + 1 < NT) {  // prefetch next B' slice; overlaps epilogue
            const char* src = bsrc + (nt+1)*BCHUNK;
            for (int c = w; c < 44; c += 8)
                GLDS16(src + c*1024 + lane*16, Bst + c*1024);
        }

        // ---- epilogue (register partials) ----
        const int j = nt*16 + jl;
        const float b1j = (j < HID) ? b1[j] : 0.f;
        const float w2j = (j < HID) ? W2[j] : 0.f;   // 0 kills pad-j contributions
        #pragma unroll
        for (int mt = 0; mt < 2; ++mt) {
            const int pt0 = q*32 + mt*16 + klo*4;
            if (g == 0) {
                const f32x4 yx = *(const f32x4*)&exch[(1*16 + jl)*XLDP + pt0];
                const f32x4 yy = *(const f32x4*)&exch[(2*16 + jl)*XLDP + pt0];
                #pragma unroll
                for (int r = 0; r < 4; ++r) {
                    float s1, c1;
                    __sincosf(acc[0][mt][r] + b1j, &s1, &c1);
                    const float wc = w2j*c1, wsn = w2j*s1;
                    pA[mt][r] += wsn;                                               // val
                    pB[mt][r] = fmaf(wc, acc[1][mt][r], fmaf(-wsn*yx[r], yx[r], pB[mt][r])); // xx
                    pC[mt][r] = fmaf(wc, acc[2][mt][r], fmaf(-wsn*yy[r], yy[r], pC[mt][r])); // yy
                }
            } else {
                const f32x4 y0 = *(const f32x4*)&exch[(0*16 + jl)*XLDP + pt0];
                #pragma unroll
                for (int r = 0; r < 4; ++r) {
                    float s1, c1;
                    __sincosf(y0[r] + b1j, &s1, &c1);
                    const float wc = w2j*c1;
                    pA[mt][r] = fmaf(wc, acc[0][mt][r], pA[mt][r]);   // dx
                    pB[mt][r] = fmaf(wc, acc[1][mt][r], pB[mt][r]);   // dy
                    pC[mt][r] = fmaf(wc, acc[2][mt][r], pC[mt][r]);   // dt
                }
            }
        }
        __syncthreads();   // exch reads done; Bst(nt+1) ready
    }

    // ---- butterfly reduce over the 16 j-lanes, then write out ----
    #pragma unroll
    for (int d = 1; d < 16; d <<= 1) {
        #pragma unroll
        for (int mt = 0; mt < 2; ++mt)
            #pragma unroll
            for (int r = 0; r < 4; ++r) {
                pA[mt][r] += __shfl_xor(pA[mt][r], d);
                pB[mt][r] += __shfl_xor(pB[mt][r], d);
                pC[mt][r] += __shfl_xor(pC[mt][r], d);
            }
    }
    if (jl == 0) {
        #pragma unroll
        for (int mt = 0; mt < 2; ++mt) {
            const int pt0 = q*32 + mt*16 + klo*4;
            f32x4 vA, vB, vC;
            #pragma unroll
            for (int r = 0; r < 4; ++r) {
                vA[r] = pA[mt][r] + ((g == 0) ? b2s : 0.f);
                vB[r] = pB[mt][r];
                vC[r] = pC[mt][r];
            }
            const int cA = (g == 0) ? colV  : colX;
            const int cB = (g == 0) ? colXX : colY;
            const int cC = (g == 0) ? colYY : colT;
            *(f32x4*)&out[(size_t)cA*Np + gp0 + pt0] = vA;
            *(f32x4*)&out[(size_t)cB*Np + gp0 + pt0] = vB;
            *(f32x4*)&out[(size_t)cC*Np + gp0 + pt0] = vC;
            #pragma unroll
            for (int r = 0; r < 4; ++r) {
                featL[(pt0+r)*13 + cA] = vA[r];
                featL[(pt0+r)*13 + cB] = vB[r];
                featL[(pt0+r)*13 + cC] = vC[r];
            }
        }
    }
}

__global__ __launch_bounds__(NTHREADS) void dhpm_main(
    const float* __restrict__ inp, const char* __restrict__ ws,
    const float* __restrict__ bu1, const float* __restrict__ Wu2, const float* __restrict__ bu2,
    const float* __restrict__ bv1, const float* __restrict__ Wv2, const float* __restrict__ bv2,
    const float* __restrict__ bf1, const float* __restrict__ Wf2, const float* __restrict__ bf2,
    float* __restrict__ out, const int Np)
{
    __shared__ __align__(16) char Bst[BCHUNK];
    __shared__ __align__(16) float exch[3*16*XLDP];   // 25344 B
    __shared__ float featL[NPTS*13];                  // 6656 B

    const int t = threadIdx.x;
    const int lane = t & 63;
    const int w = __builtin_amdgcn_readfirstlane(t >> 6);
    const int jl = lane & 15, klo = lane >> 4;
    const int gp0 = blockIdx.x * NPTS;

    run_net(inp, ws, OFF_CU, OFF_U, bu1, Wu2, bu2[0], 0, 4, 5, 6, 7, 2,
            Bst, (float*)exch, featL, out, Np, gp0);
    run_net(inp, ws, OFF_CV, OFF_V, bv1, Wv2, bv2[0], 1, 8, 9, 10, 11, 3,
            Bst, (float*)exch, featL, out, Np, gp0);

    // ======================= f-net =======================
    GLDS16(ws + OFF_F + w*1024 + lane*16, Bst + w*1024);  // stage nt=0
    __syncthreads();   // featL complete + Fst(0) ready

    f16x8 affrag[KT];
    {
        const float4* cf = (const float4*)(ws + OFF_CF);
        const int prow = w*16 + jl;
        float fv[12];
        #pragma unroll
        for (int k = 0; k < 12; ++k) fv[k] = featL[prow*13 + k];
        #pragma unroll
        for (int kt = 0; kt < KT; ++kt) {
            f16x8 f;
            #pragma unroll
            for (int e = 0; e < 8; ++e) {
                const int i = kt*32 + klo*8 + e;
                const int ic = (i < HID) ? i : 0;
                const float4 c0 = cf[ic*4+0];
                const float4 c1 = cf[ic*4+1];
                const float4 c2 = cf[ic*4+2];
                const float4 c3 = cf[ic*4+3];
                float z = c3.x;
                z = fmaf(c0.x, fv[0], z);  z = fmaf(c0.y, fv[1], z);
                z = fmaf(c0.z, fv[2], z);  z = fmaf(c0.w, fv[3], z);
                z = fmaf(c1.x, fv[4], z);  z = fmaf(c1.y, fv[5], z);
                z = fmaf(c1.z, fv[6], z);  z = fmaf(c1.w, fv[7], z);
                z = fmaf(c2.x, fv[8], z);  z = fmaf(c2.y, fv[9], z);
                z = fmaf(c2.z, fv[10], z); z = fmaf(c2.w, fv[11], z);
                f[e] = (f16)__sinf(z);
            }
            affrag[kt] = f;
        }
    }

    float pf0[4] = {0,0,0,0}, pf1[4] = {0,0,0,0};
    for (int nt = 0; nt < NT; ++nt) {
        f32x4 acc = {0.f, 0.f, 0.f, 0.f};
        const f16* F = (const f16*)Bst;
        #pragma unroll
        for (int kt = 0; kt < KT; ++kt) {
            const f16x8 bfr = *(const f16x8*)&F[jl*BLDK + kt*32 + klo*8];
            acc = __builtin_amdgcn_mfma_f32_16x16x32_f16(affrag[kt], bfr, acc, 0,0,0);
        }
        __syncthreads();   // Fst consumed
        if (nt + 1 < NT)
            GLDS16(ws + OFF_F + (nt+1)*FCHUNK + w*1024 + lane*16, Bst + w*1024);
        const int j = nt*16 + jl;
        const float bj = (j < HID) ? bf1[j] : 0.f;
        const float wa = (j < HID) ? Wf2[j] : 0.f;
        const float wb = (j < HID) ? Wf2[HID + j] : 0.f;
        #pragma unroll
        for (int r = 0; r < 4; ++r) {
            const float h = __sinf(acc[r] + bj);
            pf0[r] = fmaf(wa, h, pf0[r]);
            pf1[r] = fmaf(wb, h, pf1[r]);
        }
        __syncthreads();   // Fst(nt+1) ready
    }

    #pragma unroll
    for (int d = 1; d < 16; d <<= 1)
        #pragma unroll
        for (int r = 0; r < 4; ++r) {
            pf0[r] += __shfl_xor(pf0[r], d);
            pf1[r] += __shfl_xor(pf1[r], d);
        }
    if (jl == 0) {
        const int pt0 = w*16 + klo*4;
        f32x4 v0, v1;
        #pragma unroll
        for (int r = 0; r < 4; ++r) {
            v0[r] = pf0[r] + bf2[0];
            v1[r] = pf1[r] + bf2[1];
        }
        *(f32x4*)&out[(size_t)12*Np + gp0 + pt0] = v0;
        *(f32x4*)&out[(size_t)13*Np + gp0 + pt0] = v1;
    }
}

extern "C" void kernel_launch(void* const* d_in, const int* in_sizes, int n_in,
                              void* d_out, int out_size, void* d_ws, size_t ws_size,
                              hipStream_t stream) {
    const float* inp = (const float*)d_in[0];
    const float* Wu0 = (const float*)d_in[1];  const float* bu0 = (const float*)d_in[2];
    const float* Wu1 = (const float*)d_in[3];  const float* bu1 = (const float*)d_in[4];
    const float* Wu2 = (const float*)d_in[5];  const float* bu2 = (const float*)d_in[6];
    const float* Wv0 = (const float*)d_in[7];  const float* bv0 = (const float*)d_in[8];
    const float* Wv1 = (const float*)d_in[9];  const float* bv1 = (const float*)d_in[10];
    const float* Wv2 = (const float*)d_in[11]; const float* bv2 = (const float*)d_in[12];
    const float* Wf0 = (const float*)d_in[13]; const float* bf0 = (const float*)d_in[14];
    const float* Wf1 = (const float*)d_in[15]; const float* bf1 = (const float*)d_in[16];
    const float* Wf2 = (const float*)d_in[17]; const float* bf2 = (const float*)d_in[18];
    float* out = (float*)d_out;
    char* ws = (char*)d_ws;   // needs ~1.30 MB

    const int Np = in_sizes[0] / 3;  // 262144

    const int nTot = 2*NT*96*116 + NT*16*116 + 400 + HID;  // 314264
    dhpm_prep<<<(nTot + 255) / 256, 256, 0, stream>>>(
        Wu0, bu0, Wu1, Wv0, bv0, Wv1, Wf0, bf0, Wf1, ws);
    dhpm_main<<<Np / NPTS, NTHREADS, 0, stream>>>(
        inp, ws, bu1, Wu2, bu2, bv1, Wv2, bv2, bf1, Wf2, bf2, out, Np);
}